// Round 4
// baseline (43.670 us; speedup 1.0000x reference)
//
#include <hip/hip_runtime.h>

#define NROWS 8192
#define NCOLS 2048
#define BLOCK 512                 // one full row (512 float4) per iteration
#define RPB 16                    // rows per block
#define NCHUNK (NROWS / RPB)      // 512 row-chunks per array
#define NSLOTS (2 * NCHUNK)       // 1024 partial rows (fx then ft)
#define NQUARTER 4
#define SLOTS_PER_Q (NSLOTS / NQUARTER)   // 256

// Stage 1: each block streams a CONTIGUOUS 128 KiB stretch (16 full rows) of
// one array and writes one private partial-sum row. 4 rotating accumulators
// + full unroll -> deep load pipeline. No atomics.
__global__ void __launch_bounds__(BLOCK)
colsum_part_kernel(const float* __restrict__ fx, const float* __restrict__ ft,
                   float* __restrict__ part) {
    const int col4 = threadIdx.x;            // float4 column 0..511
    const int row0 = blockIdx.x * RPB;
    const int arr  = blockIdx.y;             // 0 = fx, 1 = ft
    const int stride4 = NCOLS / 4;           // 512

    const float4* src = reinterpret_cast<const float4*>(arr ? ft : fx)
                      + (size_t)row0 * stride4 + col4;

    float4 a0 = make_float4(0.f, 0.f, 0.f, 0.f);
    float4 a1 = make_float4(0.f, 0.f, 0.f, 0.f);
    float4 a2 = make_float4(0.f, 0.f, 0.f, 0.f);
    float4 a3 = make_float4(0.f, 0.f, 0.f, 0.f);
    #pragma unroll
    for (int r = 0; r < RPB; r += 4) {
        float4 v0 = src[(r + 0) * stride4];
        float4 v1 = src[(r + 1) * stride4];
        float4 v2 = src[(r + 2) * stride4];
        float4 v3 = src[(r + 3) * stride4];
        a0.x += v0.x; a0.y += v0.y; a0.z += v0.z; a0.w += v0.w;
        a1.x += v1.x; a1.y += v1.y; a1.z += v1.z; a1.w += v1.w;
        a2.x += v2.x; a2.y += v2.y; a2.z += v2.z; a2.w += v2.w;
        a3.x += v3.x; a3.y += v3.y; a3.z += v3.z; a3.w += v3.w;
    }
    float4 acc;
    acc.x = (a0.x + a1.x) + (a2.x + a3.x);
    acc.y = (a0.y + a1.y) + (a2.y + a3.y);
    acc.z = (a0.z + a1.z) + (a2.z + a3.z);
    acc.w = (a0.w + a1.w) + (a2.w + a3.w);

    const int slot = arr * NCHUNK + blockIdx.x;
    reinterpret_cast<float4*>(part + (size_t)slot * NCOLS)[col4] = acc;
}

// Stage 2: 1024 slots -> 4 quarter-sums per column (q0,q1 = fx; q2,q3 = ft).
// 32 blocks x 256 threads = 8192 threads = 2048 cols x 4 quarters.
__global__ void __launch_bounds__(256)
reduce_quarters_kernel(const float* __restrict__ part, float* __restrict__ sq) {
    const int gtid = blockIdx.x * 256 + threadIdx.x;
    const int k = gtid & (NCOLS - 1);
    const int q = gtid >> 11;
    const int s0 = q * SLOTS_PER_Q;

    float s = 0.f;
    #pragma unroll 8
    for (int sl = 0; sl < SLOTS_PER_Q; ++sl)
        s += part[(size_t)(s0 + sl) * NCOLS + k];
    sq[q * NCOLS + k] = s;
}

// Stage 3: s[k] = (q0+q1) - (q2+q3); out = sum s^2 / N^2. Single block.
__global__ void __launch_bounds__(256)
finalize_kernel(const float* __restrict__ sq, float* __restrict__ out) {
    __shared__ float red[4];
    const int tid = threadIdx.x;

    float acc = 0.f;
    for (int k = tid; k < NCOLS; k += 256) {
        const float s = (sq[k] + sq[NCOLS + k]) - (sq[2 * NCOLS + k] + sq[3 * NCOLS + k]);
        acc += s * s;
    }
    #pragma unroll
    for (int off = 32; off > 0; off >>= 1)
        acc += __shfl_down(acc, off, 64);
    if ((tid & 63) == 0) red[tid >> 6] = acc;
    __syncthreads();
    if (tid == 0) {
        float tot = (red[0] + red[1]) + (red[2] + red[3]);
        const double inv_n2 = 1.0 / ((double)NROWS * (double)NROWS);
        out[0] = (float)((double)tot * inv_n2);
    }
}

extern "C" void kernel_launch(void* const* d_in, const int* in_sizes, int n_in,
                              void* d_out, int out_size, void* d_ws, size_t ws_size,
                              hipStream_t stream) {
    const float* fx = (const float*)d_in[0];
    const float* ft = (const float*)d_in[1];
    float* out = (float*)d_out;
    float* part = (float*)d_ws;                  // 1024 * 2048 floats = 8 MiB
    float* sq   = part + (size_t)NSLOTS * NCOLS; // 4 * 2048 floats = 32 KiB

    // Every ws location is written before read — no memset needed.
    dim3 grid1(NCHUNK, 2);                       // 512 x 2 = 1024 blocks
    colsum_part_kernel<<<grid1, BLOCK, 0, stream>>>(fx, ft, part);

    reduce_quarters_kernel<<<NQUARTER * NCOLS / 256, 256, 0, stream>>>(part, sq);

    finalize_kernel<<<1, 256, 0, stream>>>(sq, out);
}

// Round 5
// 37.051 us; speedup vs baseline: 1.1787x; 1.1787x over previous
//
#include <hip/hip_runtime.h>

#define NROWS 8192
#define NCOLS 2048
#define ROWS_PER_BLOCK 32
#define BLOCK 256
// Stage-1 grid: x = 2 column halves, y = 256 row chunks, z = 2 arrays (fx, ft)
#define NCHUNK (NROWS / ROWS_PER_BLOCK)          // 256
#define NSLOTS (2 * NCHUNK)                      // 512 partial rows = 4 MiB
#define NQUARTER 4
#define SLOTS_PER_Q (NSLOTS / NQUARTER)          // 128

// Stage 1: per-block partial column sums. Identical structure to the round-3
// kernel (best total) EXCEPT: 8 independent accumulator chains with 8 float4
// loads issued back-to-back per unrolled group -> ~8 loads in flight per
// thread instead of ~4 (H2: memory-level-parallelism test).
__global__ void __launch_bounds__(BLOCK)
colsum_part_kernel(const float* __restrict__ fx, const float* __restrict__ ft,
                   float* __restrict__ part) {
    const int col4 = blockIdx.x * BLOCK + threadIdx.x;   // float4 column 0..511
    const int row0 = blockIdx.y * ROWS_PER_BLOCK;
    const int arr  = blockIdx.z;                         // 0 = fx, 1 = ft
    const int stride4 = NCOLS / 4;                       // 512

    const float4* src = reinterpret_cast<const float4*>(arr ? ft : fx)
                      + (size_t)row0 * stride4 + col4;

    float4 a0 = make_float4(0.f,0.f,0.f,0.f), a1 = a0, a2 = a0, a3 = a0;
    float4 a4 = a0, a5 = a0, a6 = a0, a7 = a0;

    #pragma unroll
    for (int r = 0; r < ROWS_PER_BLOCK; r += 8) {
        float4 v0 = src[(r + 0) * stride4];
        float4 v1 = src[(r + 1) * stride4];
        float4 v2 = src[(r + 2) * stride4];
        float4 v3 = src[(r + 3) * stride4];
        float4 v4 = src[(r + 4) * stride4];
        float4 v5 = src[(r + 5) * stride4];
        float4 v6 = src[(r + 6) * stride4];
        float4 v7 = src[(r + 7) * stride4];
        a0.x += v0.x; a0.y += v0.y; a0.z += v0.z; a0.w += v0.w;
        a1.x += v1.x; a1.y += v1.y; a1.z += v1.z; a1.w += v1.w;
        a2.x += v2.x; a2.y += v2.y; a2.z += v2.z; a2.w += v2.w;
        a3.x += v3.x; a3.y += v3.y; a3.z += v3.z; a3.w += v3.w;
        a4.x += v4.x; a4.y += v4.y; a4.z += v4.z; a4.w += v4.w;
        a5.x += v5.x; a5.y += v5.y; a5.z += v5.z; a5.w += v5.w;
        a6.x += v6.x; a6.y += v6.y; a6.z += v6.z; a6.w += v6.w;
        a7.x += v7.x; a7.y += v7.y; a7.z += v7.z; a7.w += v7.w;
    }
    float4 acc;
    acc.x = ((a0.x + a1.x) + (a2.x + a3.x)) + ((a4.x + a5.x) + (a6.x + a7.x));
    acc.y = ((a0.y + a1.y) + (a2.y + a3.y)) + ((a4.y + a5.y) + (a6.y + a7.y));
    acc.z = ((a0.z + a1.z) + (a2.z + a3.z)) + ((a4.z + a5.z) + (a6.z + a7.z));
    acc.w = ((a0.w + a1.w) + (a2.w + a3.w)) + ((a4.w + a5.w) + (a6.w + a7.w));

    const int slot = arr * NCHUNK + blockIdx.y;
    reinterpret_cast<float4*>(part + (size_t)slot * NCOLS)[col4] = acc;
}

// Stage 2: 512 slots -> 4 quarter-sums per column (q0,q1 = fx; q2,q3 = ft).
__global__ void __launch_bounds__(256)
reduce_quarters_kernel(const float* __restrict__ part, float* __restrict__ sq) {
    const int gtid = blockIdx.x * 256 + threadIdx.x;
    const int k = gtid & (NCOLS - 1);
    const int q = gtid >> 11;
    const int s0 = q * SLOTS_PER_Q;

    float s = 0.f;
    #pragma unroll 8
    for (int sl = 0; sl < SLOTS_PER_Q; ++sl)
        s += part[(size_t)(s0 + sl) * NCOLS + k];
    sq[q * NCOLS + k] = s;
}

// Stage 3: s[k] = (q0+q1) - (q2+q3); out = sum s^2 / N^2. Single block.
__global__ void __launch_bounds__(256)
finalize_kernel(const float* __restrict__ sq, float* __restrict__ out) {
    __shared__ float red[4];
    const int tid = threadIdx.x;

    float acc = 0.f;
    for (int k = tid; k < NCOLS; k += 256) {
        const float s = (sq[k] + sq[NCOLS + k]) - (sq[2 * NCOLS + k] + sq[3 * NCOLS + k]);
        acc += s * s;
    }
    #pragma unroll
    for (int off = 32; off > 0; off >>= 1)
        acc += __shfl_down(acc, off, 64);
    if ((tid & 63) == 0) red[tid >> 6] = acc;
    __syncthreads();
    if (tid == 0) {
        float tot = (red[0] + red[1]) + (red[2] + red[3]);
        const double inv_n2 = 1.0 / ((double)NROWS * (double)NROWS);
        out[0] = (float)((double)tot * inv_n2);
    }
}

extern "C" void kernel_launch(void* const* d_in, const int* in_sizes, int n_in,
                              void* d_out, int out_size, void* d_ws, size_t ws_size,
                              hipStream_t stream) {
    const float* fx = (const float*)d_in[0];
    const float* ft = (const float*)d_in[1];
    float* out = (float*)d_out;
    float* part = (float*)d_ws;                    // 512 * 2048 floats = 4 MiB
    float* sq   = part + (size_t)NSLOTS * NCOLS;   // 4 * 2048 floats = 32 KiB

    // Every ws location is written before read — no memset needed.
    dim3 grid1(NCOLS / 4 / BLOCK, NCHUNK, 2);      // 2 x 256 x 2 = 1024 blocks
    colsum_part_kernel<<<grid1, BLOCK, 0, stream>>>(fx, ft, part);

    reduce_quarters_kernel<<<NQUARTER * NCOLS / 256, 256, 0, stream>>>(part, sq);

    finalize_kernel<<<1, 256, 0, stream>>>(sq, out);
}

// Round 6
// 33.063 us; speedup vs baseline: 1.3208x; 1.1206x over previous
//
#include <hip/hip_runtime.h>

#define NROWS 8192
#define NCOLS 2048
#define RPB 32                      // rows per block (per array)
#define BLOCK 256
#define NCHUNK (NROWS / RPB)        // 256 row-chunks

typedef float f32x4 __attribute__((ext_vector_type(4)));

// Stage 1: partial column sums of (fx - ft), fused. Grid: x = 2 column
// halves, y = 256 row chunks. Each block reads 32 rows of BOTH arrays for
// its column half (nontemporal: zero-reuse stream) and writes one partial
// row segment. 8 independent accumulator chains, 8 loads in flight.
__global__ void __launch_bounds__(BLOCK)
colsum_part_kernel(const float* __restrict__ fx, const float* __restrict__ ft,
                   float* __restrict__ part) {
    const int col4 = blockIdx.x * BLOCK + threadIdx.x;   // float4 column 0..511
    const int row0 = blockIdx.y * RPB;
    const int stride4 = NCOLS / 4;                       // 512

    const f32x4* sx = reinterpret_cast<const f32x4*>(fx) + (size_t)row0 * stride4 + col4;
    const f32x4* st = reinterpret_cast<const f32x4*>(ft) + (size_t)row0 * stride4 + col4;

    f32x4 a0 = (f32x4)0.f, a1 = (f32x4)0.f, a2 = (f32x4)0.f, a3 = (f32x4)0.f;
    f32x4 b0 = (f32x4)0.f, b1 = (f32x4)0.f, b2 = (f32x4)0.f, b3 = (f32x4)0.f;

    #pragma unroll
    for (int r = 0; r < RPB; r += 4) {
        f32x4 x0 = __builtin_nontemporal_load(&sx[(r + 0) * stride4]);
        f32x4 x1 = __builtin_nontemporal_load(&sx[(r + 1) * stride4]);
        f32x4 x2 = __builtin_nontemporal_load(&sx[(r + 2) * stride4]);
        f32x4 x3 = __builtin_nontemporal_load(&sx[(r + 3) * stride4]);
        f32x4 t0 = __builtin_nontemporal_load(&st[(r + 0) * stride4]);
        f32x4 t1 = __builtin_nontemporal_load(&st[(r + 1) * stride4]);
        f32x4 t2 = __builtin_nontemporal_load(&st[(r + 2) * stride4]);
        f32x4 t3 = __builtin_nontemporal_load(&st[(r + 3) * stride4]);
        a0 += x0; a1 += x1; a2 += x2; a3 += x3;
        b0 += t0; b1 += t1; b2 += t2; b3 += t3;
    }
    f32x4 acc = ((a0 + a1) + (a2 + a3)) - ((b0 + b1) + (b2 + b3));

    reinterpret_cast<f32x4*>(part + (size_t)blockIdx.y * NCOLS)[col4] = acc;
}

// Stage 2 (fused finalize): 32 blocks x 256 threads. Block b owns 64 columns;
// thread (c, q) sums 64 of the 256 chunks for column c, LDS-combines the 4
// quarters, squares, wave-reduces, one scaled atomicAdd per block.
__global__ void __launch_bounds__(BLOCK)
finalize_kernel(const float* __restrict__ part, float* __restrict__ out) {
    __shared__ float sm[BLOCK];
    const int tid = threadIdx.x;
    const int col = blockIdx.x * 64 + (tid & 63);
    const int q   = tid >> 6;                      // chunk quarter 0..3

    float s = 0.f;
    #pragma unroll 8
    for (int c = 0; c < NCHUNK / 4; ++c)
        s += part[(size_t)(q * (NCHUNK / 4) + c) * NCOLS + col];
    sm[tid] = s;
    __syncthreads();

    if (tid < 64) {
        const float scol = (sm[tid] + sm[tid + 64]) + (sm[tid + 128] + sm[tid + 192]);
        float v = scol * scol;
        #pragma unroll
        for (int off = 32; off > 0; off >>= 1)
            v += __shfl_down(v, off, 64);
        if (tid == 0) {
            const float inv_n2 = (float)(1.0 / ((double)NROWS * (double)NROWS));
            atomicAdd(out, v * inv_n2);
        }
    }
}

extern "C" void kernel_launch(void* const* d_in, const int* in_sizes, int n_in,
                              void* d_out, int out_size, void* d_ws, size_t ws_size,
                              hipStream_t stream) {
    const float* fx = (const float*)d_in[0];
    const float* ft = (const float*)d_in[1];
    float* out = (float*)d_out;
    float* part = (float*)d_ws;                    // 256 * 2048 floats = 2 MiB

    // out accumulates via atomics and replays don't re-poison — zero it.
    hipMemsetAsync(out, 0, sizeof(float), stream);

    dim3 grid1(NCOLS / 4 / BLOCK, NCHUNK);         // 2 x 256 = 512 blocks
    colsum_part_kernel<<<grid1, BLOCK, 0, stream>>>(fx, ft, part);

    finalize_kernel<<<NCOLS / 64, BLOCK, 0, stream>>>(part, out);
}

// Round 7
// 28.514 us; speedup vs baseline: 1.5315x; 1.1595x over previous
//
#include <hip/hip_runtime.h>

#define NROWS 8192
#define NCOLS 2048
#define RPB 32                      // rows per block (per array)
#define BLOCK 256
#define NCHUNK (NROWS / RPB)        // 256 row-chunks

typedef float f32x4 __attribute__((ext_vector_type(4)));

// Stage 1: partial column sums of (fx - ft), fused. Grid: x = 2 column
// halves, y = 256 row chunks. Each block reads 32 rows of BOTH arrays for
// its column half (nontemporal: zero-reuse stream) and writes one partial
// row segment. 8 independent accumulator chains, 8 loads in flight.
// Block (0,0) also zeroes out[0] — visible to finalize after this kernel
// completes (stream order), so no separate memset dispatch is needed.
__global__ void __launch_bounds__(BLOCK)
colsum_part_kernel(const float* __restrict__ fx, const float* __restrict__ ft,
                   float* __restrict__ part, float* __restrict__ out) {
    if (blockIdx.x == 0 && blockIdx.y == 0 && threadIdx.x == 0)
        out[0] = 0.f;

    const int col4 = blockIdx.x * BLOCK + threadIdx.x;   // float4 column 0..511
    const int row0 = blockIdx.y * RPB;
    const int stride4 = NCOLS / 4;                       // 512

    const f32x4* sx = reinterpret_cast<const f32x4*>(fx) + (size_t)row0 * stride4 + col4;
    const f32x4* st = reinterpret_cast<const f32x4*>(ft) + (size_t)row0 * stride4 + col4;

    f32x4 a0 = (f32x4)0.f, a1 = (f32x4)0.f, a2 = (f32x4)0.f, a3 = (f32x4)0.f;
    f32x4 b0 = (f32x4)0.f, b1 = (f32x4)0.f, b2 = (f32x4)0.f, b3 = (f32x4)0.f;

    #pragma unroll
    for (int r = 0; r < RPB; r += 4) {
        f32x4 x0 = __builtin_nontemporal_load(&sx[(r + 0) * stride4]);
        f32x4 x1 = __builtin_nontemporal_load(&sx[(r + 1) * stride4]);
        f32x4 x2 = __builtin_nontemporal_load(&sx[(r + 2) * stride4]);
        f32x4 x3 = __builtin_nontemporal_load(&sx[(r + 3) * stride4]);
        f32x4 t0 = __builtin_nontemporal_load(&st[(r + 0) * stride4]);
        f32x4 t1 = __builtin_nontemporal_load(&st[(r + 1) * stride4]);
        f32x4 t2 = __builtin_nontemporal_load(&st[(r + 2) * stride4]);
        f32x4 t3 = __builtin_nontemporal_load(&st[(r + 3) * stride4]);
        a0 += x0; a1 += x1; a2 += x2; a3 += x3;
        b0 += t0; b1 += t1; b2 += t2; b3 += t3;
    }
    f32x4 acc = ((a0 + a1) + (a2 + a3)) - ((b0 + b1) + (b2 + b3));

    reinterpret_cast<f32x4*>(part + (size_t)blockIdx.y * NCOLS)[col4] = acc;
}

// Stage 2 (fused finalize): 32 blocks x 256 threads. Block b owns 64 columns;
// thread (c, q) sums 64 of the 256 chunks for column c, LDS-combines the 4
// quarters, squares, wave-reduces, one scaled atomicAdd per block.
__global__ void __launch_bounds__(BLOCK)
finalize_kernel(const float* __restrict__ part, float* __restrict__ out) {
    __shared__ float sm[BLOCK];
    const int tid = threadIdx.x;
    const int col = blockIdx.x * 64 + (tid & 63);
    const int q   = tid >> 6;                      // chunk quarter 0..3

    float s = 0.f;
    #pragma unroll 8
    for (int c = 0; c < NCHUNK / 4; ++c)
        s += part[(size_t)(q * (NCHUNK / 4) + c) * NCOLS + col];
    sm[tid] = s;
    __syncthreads();

    if (tid < 64) {
        const float scol = (sm[tid] + sm[tid + 64]) + (sm[tid + 128] + sm[tid + 192]);
        float v = scol * scol;
        #pragma unroll
        for (int off = 32; off > 0; off >>= 1)
            v += __shfl_down(v, off, 64);
        if (tid == 0) {
            const float inv_n2 = (float)(1.0 / ((double)NROWS * (double)NROWS));
            atomicAdd(out, v * inv_n2);
        }
    }
}

extern "C" void kernel_launch(void* const* d_in, const int* in_sizes, int n_in,
                              void* d_out, int out_size, void* d_ws, size_t ws_size,
                              hipStream_t stream) {
    const float* fx = (const float*)d_in[0];
    const float* ft = (const float*)d_in[1];
    float* out = (float*)d_out;
    float* part = (float*)d_ws;                    // 256 * 2048 floats = 2 MiB

    dim3 grid1(NCOLS / 4 / BLOCK, NCHUNK);         // 2 x 256 = 512 blocks
    colsum_part_kernel<<<grid1, BLOCK, 0, stream>>>(fx, ft, part, out);

    finalize_kernel<<<NCOLS / 64, BLOCK, 0, stream>>>(part, out);
}